// Round 8
// baseline (194.313 us; speedup 1.0000x reference)
//
#include <hip/hip_runtime.h>
#include <hip/hip_bf16.h>

typedef unsigned short u16;
typedef unsigned int u32;
typedef __attribute__((ext_vector_type(8))) short short8;
typedef __attribute__((ext_vector_type(4))) float f32x4;
typedef __attribute__((ext_vector_type(16))) float f32x16;

#define VMW(n) asm volatile("s_waitcnt vmcnt(" #n ")" ::: "memory")
#define BARRIER() do { asm volatile("" ::: "memory"); __builtin_amdgcn_s_barrier(); asm volatile("" ::: "memory"); } while (0)

__device__ __forceinline__ u16 f2bf(float f) {
    union { float f; unsigned int u; } v; v.f = f;
    unsigned int u = v.u;
    return (u16)((u + 0x7FFFu + ((u >> 16) & 1u)) >> 16);
}
__device__ __forceinline__ u32 pk2(float a, float b) {
    return ((u32)f2bf(b) << 16) | (u32)f2bf(a);
}
__device__ __forceinline__ void gload_lds16(const u16* g, u16* l) {
    __builtin_amdgcn_global_load_lds((const __attribute__((address_space(1))) void*)g,
                                     (__attribute__((address_space(3))) void*)l, 16, 0, 0);
}

// ---------------- prep: fp32 -> bf16 (vectorized) ----------------
__global__ void k_convert(const float* __restrict__ x, u16* __restrict__ o, int n4) {
    int i = blockIdx.x * blockDim.x + threadIdx.x;
    if (i < n4) {
        float4 v = ((const float4*)x)[i];
        ushort4 r;
        r.x = f2bf(v.x); r.y = f2bf(v.y); r.z = f2bf(v.z); r.w = f2bf(v.w);
        ((ushort4*)o)[i] = r;
    }
}

// ---------------- prep: W [K][N] fp32 -> Wt [N][K] bf16 ----------------
__global__ void k_transpose_bf(const float* __restrict__ W, u16* __restrict__ Wt, int K, int N) {
    __shared__ u16 t[32][33];
    int n0 = blockIdx.x * 32, k0 = blockIdx.y * 32;
    int tx = threadIdx.x, ty = threadIdx.y;
    #pragma unroll
    for (int i = 0; i < 4; i++) {
        t[ty + i * 8][tx] = f2bf(W[(long)(k0 + ty + i * 8) * N + n0 + tx]);
    }
    __syncthreads();
    #pragma unroll
    for (int i = 0; i < 4; i++) {
        Wt[(long)(n0 + ty + i * 8) * K + k0 + tx] = t[tx][ty + i * 8];
    }
}

// ---------------- bf16 MFMA GEMM v5: 256x256 tile, 8 waves, BK=32 units, ring-4 ----------------
// Wave-out 128x64 = 8x4 frags of 16x16x32 -> 32 MFMA per wave per unit (2x the
// old F/B density). Ring-4 32KB units (128KB LDS): stage(j+3) at iter top,
// counted VMW(8) at iter end (=> unit j+1 landed; j+2,j+3 in flight; never
// vmcnt(0) until tail), ONE barrier/iter. Slot (j+3)%4 last read at iter j-1,
// behind that iter's barrier -> WAR safe. LDS chunk swizzle (r3-proven, 0
// conflicts): slot s at row r holds global chunk s ^ ((r>>1)&3), both sides.
template<int EPI>
__global__ __launch_bounds__(512, 2) void k_gemm256(
    const u16* __restrict__ A, const u16* __restrict__ Bt, const float* __restrict__ bias,
    float* __restrict__ Cf, u16* __restrict__ q_out, u16* __restrict__ k_out, u16* __restrict__ vt_out,
    int M, int N, int K)
{
    __shared__ u16 sA[4][8192];   // [slot][256 rows][32 k]
    __shared__ u16 sB[4][8192];
    int tid = threadIdx.x;
    int w = tid >> 6, lane = tid & 63;
    int wm = w >> 2, wn = w & 3;           // 2 x 4 waves; wave out = 128 x 64
    int ln = lane & 15, gp = lane >> 4;
    int gm0 = blockIdx.x * 256, gn0 = blockIdx.y * 256;

    // staging: wave w covers rows [w*32, w*32+32) of A and B (2 gloads each).
    // lane l -> row w*32 + (l>>2), LDS chunk (l&3); source chunk (l&3)^((l>>3)&3).
    int cg = ((lane & 3) ^ ((lane >> 3) & 3)) * 8;
    const u16* aG = A  + (size_t)(gm0 + w * 32 + (lane >> 2)) * K + cg;
    const u16* bG = Bt + (size_t)(gn0 + w * 32 + (lane >> 2)) * K + cg;
    int dst = w * 1024;                    // u16 index of wave's 32-row block

    auto stage = [&](int j) {
        int sl = j & 3;
        size_t ko = (size_t)j << 5;
        gload_lds16(aG + ko,                 &sA[sl][dst]);
        gload_lds16(aG + ko + (size_t)16 * K, &sA[sl][dst + 512]);
        gload_lds16(bG + ko,                 &sB[sl][dst]);
        gload_lds16(bG + ko + (size_t)16 * K, &sB[sl][dst + 512]);
    };

    // fragment reads: row = base + ln (base % 16 == 0), chunk gp ->
    // lds chunk gp ^ ((ln>>1)&3)  (invariant over mr/nr).
    int rc = (gp ^ ((ln >> 1) & 3)) * 8;
    int abase = (wm * 128 + ln) * 32 + rc;   // + mr*512
    int bbase = (wn * 64 + ln) * 32 + rc;    // + nr*512

    f32x4 acc[8][4];
    #pragma unroll
    for (int i = 0; i < 8; i++)
        #pragma unroll
        for (int j = 0; j < 4; j++) acc[i][j] = f32x4{0.f, 0.f, 0.f, 0.f};

    int nu = K >> 5;                       // 24 for K=768 (>= 4)
    stage(0); stage(1); stage(2);
    VMW(8);                                // unit 0 landed; 1,2 in flight
    BARRIER();
    for (int j = 0; j < nu; ++j) {
        int sl = j & 3;
        if (j + 3 < nu) stage(j + 3);
        const u16* pa = &sA[sl][0];
        const u16* pb = &sB[sl][0];
        short8 bf[4], af[4], af2[4];
        #pragma unroll
        for (int nr = 0; nr < 4; nr++) bf[nr] = *(const short8*)&pb[bbase + nr * 512];
        #pragma unroll
        for (int mr = 0; mr < 4; mr++) af[mr] = *(const short8*)&pa[abase + mr * 512];
        __builtin_amdgcn_s_setprio(1);
        #pragma unroll
        for (int mr = 0; mr < 4; mr++)
            #pragma unroll
            for (int nr = 0; nr < 4; nr++)
                acc[mr][nr] = __builtin_amdgcn_mfma_f32_16x16x32_bf16(af[mr], bf[nr], acc[mr][nr], 0, 0, 0);
        __builtin_amdgcn_s_setprio(0);
        #pragma unroll
        for (int mr = 0; mr < 4; mr++) af2[mr] = *(const short8*)&pa[abase + (mr + 4) * 512];
        __builtin_amdgcn_s_setprio(1);
        #pragma unroll
        for (int mr = 0; mr < 4; mr++)
            #pragma unroll
            for (int nr = 0; nr < 4; nr++)
                acc[mr + 4][nr] = __builtin_amdgcn_mfma_f32_16x16x32_bf16(af2[mr], bf[nr], acc[mr + 4][nr], 0, 0, 0);
        __builtin_amdgcn_s_setprio(0);
        if (j + 1 < nu) {
            if (j + 3 < nu) { VMW(8); }        // unit j+1 landed; j+2,j+3 in flight
            else if (j + 2 < nu) { VMW(4); }   // only unit j+2 still in flight
            else { VMW(0); }                   // tail drain (once)
            BARRIER();
        }
    }

    #pragma unroll
    for (int mr = 0; mr < 8; mr++) {
        #pragma unroll
        for (int nr = 0; nr < 4; nr++) {
            #pragma unroll
            for (int r = 0; r < 4; r++) {
                int m = gm0 + wm * 128 + mr * 16 + gp * 4 + r;
                int n = gn0 + wn * 64 + nr * 16 + ln;
                float v = acc[mr][nr][r] + bias[n];
                if (EPI == 0) {
                    Cf[(long)m * N + n] = v;
                } else {
                    int b = m >> 10, t = m & 1023;
                    int which = n / 768, c = n % 768;
                    int h = c >> 6, d = c & 63;
                    int bh = b * 12 + h;
                    u16 bv = f2bf(v);
                    if (which == 0)      q_out[((long)bh * 1024 + t) * 64 + d] = bv;
                    else if (which == 1) k_out[((long)bh * 1024 + t) * 64 + d] = bv;
                    else                 vt_out[((long)bh * 64 + d) * 1024 + t] = bv;
                }
            }
        }
    }
}

// ---------------- causal flash attention v2: swapped 32x32 MFMA, in-register softmax ----------------
// Q,K: [BH][T][64] bf16 ; Vt: [BH][64][T] bf16 ; O: [B][T][768] bf16
__global__ __launch_bounds__(256) void k_attn(
    const u16* __restrict__ Q, const u16* __restrict__ Kb, const u16* __restrict__ Vt,
    u16* __restrict__ O)
{
    int tid = threadIdx.x, w = tid >> 6, lane = tid & 63;
    int l31 = lane & 31, hi = lane >> 5;
    int bx = blockIdx.x;
    int g = bx / 96, bh = bx - g * 96;          // g in 0..7, bh in 0..95
    int qt = g + 8 * w, q0 = qt * 32;           // wave's q-tile (work-balanced)
    int b = bh / 12, h = bh - b * 12;
    const u16* Qb  = Q  + (size_t)bh * 65536;
    const u16* Kbb = Kb + (size_t)bh * 65536;
    const u16* Vb  = Vt + (size_t)bh * 65536;

    short8 qf[4];
    #pragma unroll
    for (int ch = 0; ch < 4; ch++)
        qf[ch] = *(const short8*)&Qb[(q0 + l31) * 64 + ch * 16 + hi * 8];

    f32x16 o0 = {}, o1 = {};
    float mrun = -INFINITY, lsum = 0.f;
    const float SC = 0.18033688011f;            // 0.125 * log2(e)

    int nit = qt + 1;
    for (int it = 0; it < nit; it++) {
        int kt = it * 32;
        f32x16 s = {};
        #pragma unroll
        for (int ch = 0; ch < 4; ch++) {
            short8 kf = *(const short8*)&Kbb[(kt + l31) * 64 + ch * 16 + hi * 8];
            s = __builtin_amdgcn_mfma_f32_32x32x16_bf16(kf, qf[ch], s, 0, 0, 0);
        }
        float ps[16];
        int qg = q0 + l31;
        #pragma unroll
        for (int r = 0; r < 16; r++) {
            int krow = kt + (r & 3) + 8 * (r >> 2) + 4 * hi;
            ps[r] = (krow <= qg) ? s[r] * SC : -1e30f;
        }
        float t8[8];
        #pragma unroll
        for (int i = 0; i < 8; i++) t8[i] = fmaxf(ps[i], ps[i + 8]);
        float t4a = fmaxf(t8[0], t8[1]), t4b = fmaxf(t8[2], t8[3]);
        float t4c = fmaxf(t8[4], t8[5]), t4d = fmaxf(t8[6], t8[7]);
        float tm = fmaxf(fmaxf(t4a, t4b), fmaxf(t4c, t4d));
        tm = fmaxf(tm, __shfl_xor(tm, 32));
        float mn = fmaxf(mrun, tm);
        float scale = exp2f(mrun - mn);
        mrun = mn;
        float rs = 0.f;
        #pragma unroll
        for (int r = 0; r < 16; r++) { ps[r] = exp2f(ps[r] - mn); rs += ps[r]; }
        rs += __shfl_xor(rs, 32);
        lsum = lsum * scale + rs;
        #pragma unroll
        for (int r = 0; r < 16; r++) { o0[r] *= scale; o1[r] *= scale; }
        u32 c[8], sw[8];
        #pragma unroll
        for (int i = 0; i < 8; i++) c[i] = pk2(ps[2 * i], ps[2 * i + 1]);
        #pragma unroll
        for (int i = 0; i < 8; i++) sw[i] = (u32)__shfl_xor((int)c[i], 32);
        union { u32 u[4]; short8 s8; } pb0, pb1;
        pb0.u[0] = hi ? sw[2] : c[0];
        pb0.u[1] = hi ? sw[3] : c[1];
        pb0.u[2] = hi ? c[2]  : sw[0];
        pb0.u[3] = hi ? c[3]  : sw[1];
        pb1.u[0] = hi ? sw[6] : c[4];
        pb1.u[1] = hi ? sw[7] : c[5];
        pb1.u[2] = hi ? c[6]  : sw[4];
        pb1.u[3] = hi ? c[7]  : sw[5];
        #pragma unroll
        for (int kh = 0; kh < 2; kh++) {
            const short8* pbp = kh ? &pb1.s8 : &pb0.s8;
            short8 vf0 = *(const short8*)&Vb[(size_t)l31 * 1024 + kt + kh * 16 + hi * 8];
            short8 vf1 = *(const short8*)&Vb[(size_t)(32 + l31) * 1024 + kt + kh * 16 + hi * 8];
            o0 = __builtin_amdgcn_mfma_f32_32x32x16_bf16(vf0, *pbp, o0, 0, 0, 0);
            o1 = __builtin_amdgcn_mfma_f32_32x32x16_bf16(vf1, *pbp, o1, 0, 0, 0);
        }
    }

    float inv = 1.0f / lsum;
    int t = q0 + l31;
    size_t base = ((size_t)(b * 1024 + t)) * 768 + h * 64;
    #pragma unroll
    for (int rq = 0; rq < 4; rq++) {
        ushort4 u0, u1;
        u0.x = f2bf(o0[4 * rq + 0] * inv); u0.y = f2bf(o0[4 * rq + 1] * inv);
        u0.z = f2bf(o0[4 * rq + 2] * inv); u0.w = f2bf(o0[4 * rq + 3] * inv);
        u1.x = f2bf(o1[4 * rq + 0] * inv); u1.y = f2bf(o1[4 * rq + 1] * inv);
        u1.z = f2bf(o1[4 * rq + 2] * inv); u1.w = f2bf(o1[4 * rq + 3] * inv);
        *(ushort4*)&O[base + rq * 8 + hi * 4]      = u0;
        *(ushort4*)&O[base + 32 + rq * 8 + hi * 4] = u1;
    }
}

extern "C" void kernel_launch(void* const* d_in, const int* in_sizes, int n_in,
                              void* d_out, int out_size, void* d_ws, size_t ws_size,
                              hipStream_t stream)
{
    const float* x     = (const float*)d_in[0];
    const float* W_qkv = (const float*)d_in[1];
    const float* b_qkv = (const float*)d_in[2];
    const float* W_out = (const float*)d_in[3];
    const float* b_out = (const float*)d_in[4];
    float* out = (float*)d_out;

    char* w = (char*)d_ws;
    u16* xb  = (u16*)w; w += (size_t)8192 * 768 * 2;
    u16* wqt = (u16*)w; w += (size_t)2304 * 768 * 2;
    u16* wot = (u16*)w; w += (size_t)768 * 768 * 2;
    u16* qb  = (u16*)w; w += (size_t)96 * 1024 * 64 * 2;
    u16* kb  = (u16*)w; w += (size_t)96 * 1024 * 64 * 2;
    u16* vt  = (u16*)w; w += (size_t)96 * 64 * 1024 * 2;
    u16* ao  = (u16*)w; w += (size_t)8192 * 768 * 2;

    k_convert<<<dim3(6144), 256, 0, stream>>>(x, xb, 1572864);
    k_transpose_bf<<<dim3(72, 24), dim3(32, 8), 0, stream>>>(W_qkv, wqt, 768, 2304);
    k_transpose_bf<<<dim3(24, 24), dim3(32, 8), 0, stream>>>(W_out, wot, 768, 768);
    k_gemm256<1><<<dim3(32, 9), 512, 0, stream>>>(xb, wqt, b_qkv, nullptr, qb, kb, vt, 8192, 2304, 768);
    k_attn<<<dim3(768), 256, 0, stream>>>(qb, kb, vt, ao);
    k_gemm256<0><<<dim3(32, 3), 512, 0, stream>>>(ao, wot, b_out, out, nullptr, nullptr, nullptr, 8192, 768, 768);
}

// Round 9
// 152.618 us; speedup vs baseline: 1.2732x; 1.2732x over previous
//
#include <hip/hip_runtime.h>
#include <hip/hip_bf16.h>

typedef unsigned short u16;
typedef unsigned int u32;
typedef __attribute__((ext_vector_type(8))) short short8;
typedef __attribute__((ext_vector_type(4))) float f32x4;
typedef __attribute__((ext_vector_type(16))) float f32x16;

__device__ __forceinline__ u16 f2bf(float f) {
    union { float f; unsigned int u; } v; v.f = f;
    unsigned int u = v.u;
    return (u16)((u + 0x7FFFu + ((u >> 16) & 1u)) >> 16);
}
__device__ __forceinline__ u32 pk2(float a, float b) {
    return ((u32)f2bf(b) << 16) | (u32)f2bf(a);
}

// ---------------- prep: W [K][N] fp32 -> Wt [N][K] bf16 ----------------
__global__ void k_transpose_bf(const float* __restrict__ W, u16* __restrict__ Wt, int K, int N) {
    __shared__ u16 t[32][33];
    int n0 = blockIdx.x * 32, k0 = blockIdx.y * 32;
    int tx = threadIdx.x, ty = threadIdx.y;
    #pragma unroll
    for (int i = 0; i < 4; i++) {
        t[ty + i * 8][tx] = f2bf(W[(long)(k0 + ty + i * 8) * N + n0 + tx]);
    }
    __syncthreads();
    #pragma unroll
    for (int i = 0; i < 4; i++) {
        Wt[(long)(n0 + ty + i * 8) * K + k0 + tx] = t[tx][ty + i * 8];
    }
}

// ---------------- bf16 MFMA GEMM (r1-proven structure + dbuf + fused A-convert) ----
// Reg-staged staging (compiler hoists next-tile global loads over current-tile
// MFMAs => T14 issue-early/write-late for free), padded [128][40] LDS (2-way
// bank alias = free, m136), 128x128 tile, 4 waves, BK=32, ONE barrier/K-step
// via double-buffered halves. AF32=1: A is fp32, converted to bf16 in-register
// during staging (k_convert fused away).
template<int EPI, int AF32>
__global__ __launch_bounds__(256) void k_gemm_bt(
    const void* __restrict__ Av, const u16* __restrict__ Bt, const float* __restrict__ bias,
    float* __restrict__ Cf, u16* __restrict__ q_out, u16* __restrict__ k_out, u16* __restrict__ vt_out,
    int M, int N, int K)
{
    __shared__ u16 lA[2][128][40];   // +8 pad: 80B row stride, 16B-aligned
    __shared__ u16 lB[2][128][40];
    int tid = threadIdx.x;
    int wid = tid >> 6, lane = tid & 63;
    int wm = wid >> 1, wn = wid & 1;
    int ln = lane & 15, gp = lane >> 4;
    int gm0 = blockIdx.x * 128, gn0 = blockIdx.y * 128;

    const float* Af = (const float*)Av;
    const u16*   Ab = (const u16*)Av;

    f32x4 zf = {0.f, 0.f, 0.f, 0.f};
    f32x4 acc[4][4];
    #pragma unroll
    for (int i = 0; i < 4; i++)
        #pragma unroll
        for (int j = 0; j < 4; j++) acc[i][j] = zf;

    int sr = tid >> 2;          // staging row (0..63), +64 for second chunk
    int sc = (tid & 3) * 8;     // staging col (elements), 16B chunks

    short8 rA0, rA1, rB0, rB1;  // staging registers (issue-early)
    auto gload = [&](int k0) {
        if (AF32) {
            float4 a0l = *(const float4*)&Af[(size_t)(gm0 + sr) * K + k0 + sc];
            float4 a0h = *(const float4*)&Af[(size_t)(gm0 + sr) * K + k0 + sc + 4];
            float4 a1l = *(const float4*)&Af[(size_t)(gm0 + sr + 64) * K + k0 + sc];
            float4 a1h = *(const float4*)&Af[(size_t)(gm0 + sr + 64) * K + k0 + sc + 4];
            union { u32 u[4]; short8 s8; } p0, p1;
            p0.u[0] = pk2(a0l.x, a0l.y); p0.u[1] = pk2(a0l.z, a0l.w);
            p0.u[2] = pk2(a0h.x, a0h.y); p0.u[3] = pk2(a0h.z, a0h.w);
            p1.u[0] = pk2(a1l.x, a1l.y); p1.u[1] = pk2(a1l.z, a1l.w);
            p1.u[2] = pk2(a1h.x, a1h.y); p1.u[3] = pk2(a1h.z, a1h.w);
            rA0 = p0.s8; rA1 = p1.s8;
        } else {
            rA0 = *(const short8*)&Ab[(size_t)(gm0 + sr) * K + k0 + sc];
            rA1 = *(const short8*)&Ab[(size_t)(gm0 + sr + 64) * K + k0 + sc];
        }
        rB0 = *(const short8*)&Bt[(size_t)(gn0 + sr) * K + k0 + sc];
        rB1 = *(const short8*)&Bt[(size_t)(gn0 + sr + 64) * K + k0 + sc];
    };
    auto swrite = [&](int bb) {
        *(short8*)&lA[bb][sr][sc]      = rA0;
        *(short8*)&lA[bb][sr + 64][sc] = rA1;
        *(short8*)&lB[bb][sr][sc]      = rB0;
        *(short8*)&lB[bb][sr + 64][sc] = rB1;
    };

    int nk = K >> 5;
    gload(0);
    swrite(0);
    __syncthreads();
    #pragma unroll 2
    for (int t = 0; t < nk; ++t) {
        int cur = t & 1;
        if (t + 1 < nk) gload((t + 1) << 5);   // issue early; latency under MFMAs
        short8 af[4], bfr[4];
        #pragma unroll
        for (int i = 0; i < 4; i++) {
            af[i]  = *(const short8*)&lA[cur][wm * 64 + i * 16 + ln][gp * 8];
            bfr[i] = *(const short8*)&lB[cur][wn * 64 + i * 16 + ln][gp * 8];
        }
        #pragma unroll
        for (int i = 0; i < 4; i++)
            #pragma unroll
            for (int j = 0; j < 4; j++)
                acc[i][j] = __builtin_amdgcn_mfma_f32_16x16x32_bf16(af[i], bfr[j], acc[i][j], 0, 0, 0);
        if (t + 1 < nk) swrite(cur ^ 1);       // write-late into other half
        __syncthreads();                        // covers write->read and read->rewrite
    }

    #pragma unroll
    for (int i = 0; i < 4; i++) {
        #pragma unroll
        for (int j = 0; j < 4; j++) {
            #pragma unroll
            for (int r = 0; r < 4; r++) {
                int m = gm0 + wm * 64 + i * 16 + gp * 4 + r;
                int n = gn0 + wn * 64 + j * 16 + ln;
                float v = acc[i][j][r] + bias[n];
                if (EPI == 0) {
                    Cf[(long)m * N + n] = v;
                } else {
                    int b = m >> 10, t = m & 1023;
                    int which = n / 768, c = n % 768;
                    int h = c >> 6, d = c & 63;
                    int bh = b * 12 + h;
                    u16 bv = f2bf(v);
                    if (which == 0)      q_out[((long)bh * 1024 + t) * 64 + d] = bv;
                    else if (which == 1) k_out[((long)bh * 1024 + t) * 64 + d] = bv;
                    else                 vt_out[((long)bh * 64 + d) * 1024 + t] = bv;
                }
            }
        }
    }
}

// ---------------- causal flash attention v2: swapped 32x32 MFMA, in-register softmax ----------------
// Q,K: [BH][T][64] bf16 ; Vt: [BH][64][T] bf16 ; O: [B][T][768] bf16
__global__ __launch_bounds__(256) void k_attn(
    const u16* __restrict__ Q, const u16* __restrict__ Kb, const u16* __restrict__ Vt,
    u16* __restrict__ O)
{
    int tid = threadIdx.x, w = tid >> 6, lane = tid & 63;
    int l31 = lane & 31, hi = lane >> 5;
    int bx = blockIdx.x;
    int g = bx / 96, bh = bx - g * 96;          // g in 0..7, bh in 0..95
    int qt = g + 8 * w, q0 = qt * 32;           // wave's q-tile (work-balanced)
    int b = bh / 12, h = bh - b * 12;
    const u16* Qb  = Q  + (size_t)bh * 65536;
    const u16* Kbb = Kb + (size_t)bh * 65536;
    const u16* Vb  = Vt + (size_t)bh * 65536;

    short8 qf[4];
    #pragma unroll
    for (int ch = 0; ch < 4; ch++)
        qf[ch] = *(const short8*)&Qb[(q0 + l31) * 64 + ch * 16 + hi * 8];

    f32x16 o0 = {}, o1 = {};
    float mrun = -INFINITY, lsum = 0.f;
    const float SC = 0.18033688011f;            // 0.125 * log2(e)

    int nit = qt + 1;
    for (int it = 0; it < nit; it++) {
        int kt = it * 32;
        f32x16 s = {};
        #pragma unroll
        for (int ch = 0; ch < 4; ch++) {
            short8 kf = *(const short8*)&Kbb[(kt + l31) * 64 + ch * 16 + hi * 8];
            s = __builtin_amdgcn_mfma_f32_32x32x16_bf16(kf, qf[ch], s, 0, 0, 0);
        }
        float ps[16];
        int qg = q0 + l31;
        #pragma unroll
        for (int r = 0; r < 16; r++) {
            int krow = kt + (r & 3) + 8 * (r >> 2) + 4 * hi;
            ps[r] = (krow <= qg) ? s[r] * SC : -1e30f;
        }
        float t8[8];
        #pragma unroll
        for (int i = 0; i < 8; i++) t8[i] = fmaxf(ps[i], ps[i + 8]);
        float t4a = fmaxf(t8[0], t8[1]), t4b = fmaxf(t8[2], t8[3]);
        float t4c = fmaxf(t8[4], t8[5]), t4d = fmaxf(t8[6], t8[7]);
        float tm = fmaxf(fmaxf(t4a, t4b), fmaxf(t4c, t4d));
        tm = fmaxf(tm, __shfl_xor(tm, 32));
        float mn = fmaxf(mrun, tm);
        float scale = exp2f(mrun - mn);
        mrun = mn;
        float rs = 0.f;
        #pragma unroll
        for (int r = 0; r < 16; r++) { ps[r] = exp2f(ps[r] - mn); rs += ps[r]; }
        rs += __shfl_xor(rs, 32);
        lsum = lsum * scale + rs;
        #pragma unroll
        for (int r = 0; r < 16; r++) { o0[r] *= scale; o1[r] *= scale; }
        u32 c[8], sw[8];
        #pragma unroll
        for (int i = 0; i < 8; i++) c[i] = pk2(ps[2 * i], ps[2 * i + 1]);
        #pragma unroll
        for (int i = 0; i < 8; i++) sw[i] = (u32)__shfl_xor((int)c[i], 32);
        union { u32 u[4]; short8 s8; } pb0, pb1;
        pb0.u[0] = hi ? sw[2] : c[0];
        pb0.u[1] = hi ? sw[3] : c[1];
        pb0.u[2] = hi ? c[2]  : sw[0];
        pb0.u[3] = hi ? c[3]  : sw[1];
        pb1.u[0] = hi ? sw[6] : c[4];
        pb1.u[1] = hi ? sw[7] : c[5];
        pb1.u[2] = hi ? c[6]  : sw[4];
        pb1.u[3] = hi ? c[7]  : sw[5];
        #pragma unroll
        for (int kh = 0; kh < 2; kh++) {
            const short8* pbp = kh ? &pb1.s8 : &pb0.s8;
            short8 vf0 = *(const short8*)&Vb[(size_t)l31 * 1024 + kt + kh * 16 + hi * 8];
            short8 vf1 = *(const short8*)&Vb[(size_t)(32 + l31) * 1024 + kt + kh * 16 + hi * 8];
            o0 = __builtin_amdgcn_mfma_f32_32x32x16_bf16(vf0, *pbp, o0, 0, 0, 0);
            o1 = __builtin_amdgcn_mfma_f32_32x32x16_bf16(vf1, *pbp, o1, 0, 0, 0);
        }
    }

    float inv = 1.0f / lsum;
    int t = q0 + l31;
    size_t base = ((size_t)(b * 1024 + t)) * 768 + h * 64;
    #pragma unroll
    for (int rq = 0; rq < 4; rq++) {
        ushort4 u0, u1;
        u0.x = f2bf(o0[4 * rq + 0] * inv); u0.y = f2bf(o0[4 * rq + 1] * inv);
        u0.z = f2bf(o0[4 * rq + 2] * inv); u0.w = f2bf(o0[4 * rq + 3] * inv);
        u1.x = f2bf(o1[4 * rq + 0] * inv); u1.y = f2bf(o1[4 * rq + 1] * inv);
        u1.z = f2bf(o1[4 * rq + 2] * inv); u1.w = f2bf(o1[4 * rq + 3] * inv);
        *(ushort4*)&O[base + rq * 8 + hi * 4]      = u0;
        *(ushort4*)&O[base + 32 + rq * 8 + hi * 4] = u1;
    }
}

extern "C" void kernel_launch(void* const* d_in, const int* in_sizes, int n_in,
                              void* d_out, int out_size, void* d_ws, size_t ws_size,
                              hipStream_t stream)
{
    const float* x     = (const float*)d_in[0];
    const float* W_qkv = (const float*)d_in[1];
    const float* b_qkv = (const float*)d_in[2];
    const float* W_out = (const float*)d_in[3];
    const float* b_out = (const float*)d_in[4];
    float* out = (float*)d_out;

    char* w = (char*)d_ws;
    u16* wqt = (u16*)w; w += (size_t)2304 * 768 * 2;
    u16* wot = (u16*)w; w += (size_t)768 * 768 * 2;
    u16* qb  = (u16*)w; w += (size_t)96 * 1024 * 64 * 2;
    u16* kb  = (u16*)w; w += (size_t)96 * 1024 * 64 * 2;
    u16* vt  = (u16*)w; w += (size_t)96 * 64 * 1024 * 2;
    u16* ao  = (u16*)w; w += (size_t)8192 * 768 * 2;

    k_transpose_bf<<<dim3(72, 24), dim3(32, 8), 0, stream>>>(W_qkv, wqt, 768, 2304);
    k_transpose_bf<<<dim3(24, 24), dim3(32, 8), 0, stream>>>(W_out, wot, 768, 768);
    k_gemm_bt<1, 1><<<dim3(64, 18), 256, 0, stream>>>(x, wqt, b_qkv, nullptr, qb, kb, vt, 8192, 2304, 768);
    k_attn<<<dim3(768), 256, 0, stream>>>(qb, kb, vt, ao);
    k_gemm_bt<0, 0><<<dim3(64, 6), 256, 0, stream>>>(ao, wot, b_out, out, nullptr, nullptr, nullptr, 8192, 768, 768);
}

// Round 10
// 151.192 us; speedup vs baseline: 1.2852x; 1.0094x over previous
//
#include <hip/hip_runtime.h>
#include <hip/hip_bf16.h>

typedef unsigned short u16;
typedef unsigned int u32;
typedef __attribute__((ext_vector_type(8))) short short8;
typedef __attribute__((ext_vector_type(4))) float f32x4;
typedef __attribute__((ext_vector_type(16))) float f32x16;
typedef __attribute__((ext_vector_type(4))) unsigned int uint4v;

__device__ __forceinline__ u16 f2bf(float f) {
    union { float f; unsigned int u; } v; v.f = f;
    unsigned int u = v.u;
    return (u16)((u + 0x7FFFu + ((u >> 16) & 1u)) >> 16);
}
__device__ __forceinline__ u32 pk2(float a, float b) {
    return ((u32)f2bf(b) << 16) | (u32)f2bf(a);
}

// ---------------- prep: fp32 -> bf16 (vectorized) ----------------
__global__ void k_convert(const float* __restrict__ x, u16* __restrict__ o, int n4) {
    int i = blockIdx.x * blockDim.x + threadIdx.x;
    if (i < n4) {
        float4 v = ((const float4*)x)[i];
        ushort4 r;
        r.x = f2bf(v.x); r.y = f2bf(v.y); r.z = f2bf(v.z); r.w = f2bf(v.w);
        ((ushort4*)o)[i] = r;
    }
}

// ---------------- prep: W [K][N] fp32 -> Wt [N][K] bf16 ----------------
__global__ void k_transpose_bf(const float* __restrict__ W, u16* __restrict__ Wt, int K, int N) {
    __shared__ u16 t[32][33];
    int n0 = blockIdx.x * 32, k0 = blockIdx.y * 32;
    int tx = threadIdx.x, ty = threadIdx.y;
    #pragma unroll
    for (int i = 0; i < 4; i++) {
        t[ty + i * 8][tx] = f2bf(W[(long)(k0 + ty + i * 8) * N + n0 + tx]);
    }
    __syncthreads();
    #pragma unroll
    for (int i = 0; i < 4; i++) {
        Wt[(long)(n0 + ty + i * 8) * K + k0 + tx] = t[tx][ty + i * 8];
    }
}

// ---------------- prep: qkv V-columns -> Vt [BH][64][1024] (coalesced transpose) ----
__global__ void k_vt(const u16* __restrict__ qkv, u16* __restrict__ vt) {
    __shared__ u16 s[32][33];
    int t0 = blockIdx.x * 32, d0 = blockIdx.y * 32, bh = blockIdx.z;
    int b = bh / 12, h = bh - b * 12;
    int tx = threadIdx.x, ty = threadIdx.y;
    const u16* src = qkv + (size_t)(b * 1024 + t0) * 2304 + 1536 + h * 64 + d0;
    #pragma unroll
    for (int i = 0; i < 4; i++) {
        s[ty + i * 8][tx] = src[(size_t)(ty + i * 8) * 2304 + tx];
    }
    __syncthreads();
    u16* dst = vt + (size_t)bh * 65536 + (size_t)d0 * 1024 + t0;
    #pragma unroll
    for (int i = 0; i < 4; i++) {
        dst[(size_t)(ty + i * 8) * 1024 + tx] = s[tx][ty + i * 8];
    }
}

// ---------------- bf16 MFMA GEMM: r1-exact inner loop, uniform epilogue ----------------
// Single 20KB padded LDS (8 blocks/CU), 2 barriers/K-step, reg-staged bf16
// (compiler hoists next loads across barriers). EPI=0: fp32 out. EPI=2: bf16
// row-major out (QKV: no scatter -- V^T handled by k_vt).
template<int EPI>
__global__ __launch_bounds__(256) void k_gemm_bt(
    const u16* __restrict__ A, const u16* __restrict__ Bt, const float* __restrict__ bias,
    float* __restrict__ Cf, u16* __restrict__ Cb,
    int M, int N, int K)
{
    __shared__ u16 lA[128][40];   // +8 pad: 80B row stride, 2-way alias = free
    __shared__ u16 lB[128][40];
    int tid = threadIdx.x;
    int wid = tid >> 6, lane = tid & 63;
    int wm = wid >> 1, wn = wid & 1;
    int ln = lane & 15, gp = lane >> 4;
    int gm0 = blockIdx.x * 128, gn0 = blockIdx.y * 128;

    f32x4 zf = {0.f, 0.f, 0.f, 0.f};
    f32x4 acc[4][4];
    #pragma unroll
    for (int i = 0; i < 4; i++)
        #pragma unroll
        for (int j = 0; j < 4; j++) acc[i][j] = zf;

    int sr = tid >> 2;          // staging row (0..63), +64 for second chunk
    int sc = (tid & 3) * 8;     // staging col (elements), 16B chunks

    for (int k0 = 0; k0 < K; k0 += 32) {
        #pragma unroll
        for (int j = 0; j < 2; j++) {
            int r = sr + j * 64;
            *(uint4v*)&lA[r][sc] = *(const uint4v*)&A[(long)(gm0 + r) * K + k0 + sc];
            *(uint4v*)&lB[r][sc] = *(const uint4v*)&Bt[(long)(gn0 + r) * K + k0 + sc];
        }
        __syncthreads();
        short8 af[4], bfr[4];
        #pragma unroll
        for (int i = 0; i < 4; i++) {
            af[i]  = *(const short8*)&lA[wm * 64 + i * 16 + ln][gp * 8];
            bfr[i] = *(const short8*)&lB[wn * 64 + i * 16 + ln][gp * 8];
        }
        #pragma unroll
        for (int i = 0; i < 4; i++)
            #pragma unroll
            for (int j = 0; j < 4; j++)
                acc[i][j] = __builtin_amdgcn_mfma_f32_16x16x32_bf16(af[i], bfr[j], acc[i][j], 0, 0, 0);
        __syncthreads();
    }

    #pragma unroll
    for (int i = 0; i < 4; i++) {
        #pragma unroll
        for (int j = 0; j < 4; j++) {
            #pragma unroll
            for (int r = 0; r < 4; r++) {
                int m = gm0 + wm * 64 + i * 16 + gp * 4 + r;
                int n = gn0 + wn * 64 + j * 16 + ln;
                float v = acc[i][j][r] + bias[n];
                if (EPI == 0) Cf[(long)m * N + n] = v;
                else          Cb[(long)m * N + n] = f2bf(v);
            }
        }
    }
}

// ---------------- causal flash attention: swapped 32x32 MFMA, in-register softmax ----------------
// Q,K read from qkv [8192][2304] (row stride 2304); Vt: [BH][64][1024] bf16.
__global__ __launch_bounds__(256) void k_attn(
    const u16* __restrict__ qkv, const u16* __restrict__ Vt,
    u16* __restrict__ O)
{
    int tid = threadIdx.x, w = tid >> 6, lane = tid & 63;
    int l31 = lane & 31, hi = lane >> 5;
    int bx = blockIdx.x;
    int g = bx / 96, bh = bx - g * 96;          // g in 0..7, bh in 0..95
    int qt = g + 8 * w, q0 = qt * 32;           // wave's q-tile (work-balanced)
    int b = bh / 12, h = bh - b * 12;
    const u16* Qb  = qkv + (size_t)(b * 1024) * 2304 + h * 64;          // row stride 2304
    const u16* Kbb = Qb + 768;
    const u16* Vb  = Vt + (size_t)bh * 65536;

    short8 qf[4];
    #pragma unroll
    for (int ch = 0; ch < 4; ch++)
        qf[ch] = *(const short8*)&Qb[(size_t)(q0 + l31) * 2304 + ch * 16 + hi * 8];

    f32x16 o0 = {}, o1 = {};
    float mrun = -INFINITY, lsum = 0.f;
    const float SC = 0.18033688011f;            // 0.125 * log2(e)

    int nit = qt + 1;
    for (int it = 0; it < nit; it++) {
        int kt = it * 32;
        f32x16 s = {};
        #pragma unroll
        for (int ch = 0; ch < 4; ch++) {
            short8 kf = *(const short8*)&Kbb[(size_t)(kt + l31) * 2304 + ch * 16 + hi * 8];
            s = __builtin_amdgcn_mfma_f32_32x32x16_bf16(kf, qf[ch], s, 0, 0, 0);
        }
        float ps[16];
        int qg = q0 + l31;
        #pragma unroll
        for (int r = 0; r < 16; r++) {
            int krow = kt + (r & 3) + 8 * (r >> 2) + 4 * hi;
            ps[r] = (krow <= qg) ? s[r] * SC : -1e30f;
        }
        float t8[8];
        #pragma unroll
        for (int i = 0; i < 8; i++) t8[i] = fmaxf(ps[i], ps[i + 8]);
        float t4a = fmaxf(t8[0], t8[1]), t4b = fmaxf(t8[2], t8[3]);
        float t4c = fmaxf(t8[4], t8[5]), t4d = fmaxf(t8[6], t8[7]);
        float tm = fmaxf(fmaxf(t4a, t4b), fmaxf(t4c, t4d));
        tm = fmaxf(tm, __shfl_xor(tm, 32));
        float mn = fmaxf(mrun, tm);
        float scale = exp2f(mrun - mn);
        mrun = mn;
        float rs = 0.f;
        #pragma unroll
        for (int r = 0; r < 16; r++) { ps[r] = exp2f(ps[r] - mn); rs += ps[r]; }
        rs += __shfl_xor(rs, 32);
        lsum = lsum * scale + rs;
        #pragma unroll
        for (int r = 0; r < 16; r++) { o0[r] *= scale; o1[r] *= scale; }
        u32 c[8], sw[8];
        #pragma unroll
        for (int i = 0; i < 8; i++) c[i] = pk2(ps[2 * i], ps[2 * i + 1]);
        #pragma unroll
        for (int i = 0; i < 8; i++) sw[i] = (u32)__shfl_xor((int)c[i], 32);
        union { u32 u[4]; short8 s8; } pb0, pb1;
        pb0.u[0] = hi ? sw[2] : c[0];
        pb0.u[1] = hi ? sw[3] : c[1];
        pb0.u[2] = hi ? c[2]  : sw[0];
        pb0.u[3] = hi ? c[3]  : sw[1];
        pb1.u[0] = hi ? sw[6] : c[4];
        pb1.u[1] = hi ? sw[7] : c[5];
        pb1.u[2] = hi ? c[6]  : sw[4];
        pb1.u[3] = hi ? c[7]  : sw[5];
        #pragma unroll
        for (int kh = 0; kh < 2; kh++) {
            const short8* pbp = kh ? &pb1.s8 : &pb0.s8;
            short8 vf0 = *(const short8*)&Vb[(size_t)l31 * 1024 + kt + kh * 16 + hi * 8];
            short8 vf1 = *(const short8*)&Vb[(size_t)(32 + l31) * 1024 + kt + kh * 16 + hi * 8];
            o0 = __builtin_amdgcn_mfma_f32_32x32x16_bf16(vf0, *pbp, o0, 0, 0, 0);
            o1 = __builtin_amdgcn_mfma_f32_32x32x16_bf16(vf1, *pbp, o1, 0, 0, 0);
        }
    }

    float inv = 1.0f / lsum;
    int t = q0 + l31;
    size_t base = ((size_t)(b * 1024 + t)) * 768 + h * 64;
    #pragma unroll
    for (int rq = 0; rq < 4; rq++) {
        ushort4 u0, u1;
        u0.x = f2bf(o0[4 * rq + 0] * inv); u0.y = f2bf(o0[4 * rq + 1] * inv);
        u0.z = f2bf(o0[4 * rq + 2] * inv); u0.w = f2bf(o0[4 * rq + 3] * inv);
        u1.x = f2bf(o1[4 * rq + 0] * inv); u1.y = f2bf(o1[4 * rq + 1] * inv);
        u1.z = f2bf(o1[4 * rq + 2] * inv); u1.w = f2bf(o1[4 * rq + 3] * inv);
        *(ushort4*)&O[base + rq * 8 + hi * 4]      = u0;
        *(ushort4*)&O[base + 32 + rq * 8 + hi * 4] = u1;
    }
}

extern "C" void kernel_launch(void* const* d_in, const int* in_sizes, int n_in,
                              void* d_out, int out_size, void* d_ws, size_t ws_size,
                              hipStream_t stream)
{
    const float* x     = (const float*)d_in[0];
    const float* W_qkv = (const float*)d_in[1];
    const float* b_qkv = (const float*)d_in[2];
    const float* W_out = (const float*)d_in[3];
    const float* b_out = (const float*)d_in[4];
    float* out = (float*)d_out;

    char* w = (char*)d_ws;
    u16* xb  = (u16*)w; w += (size_t)8192 * 768 * 2;
    u16* wqt = (u16*)w; w += (size_t)2304 * 768 * 2;
    u16* wot = (u16*)w; w += (size_t)768 * 768 * 2;
    u16* qkv = (u16*)w; w += (size_t)8192 * 2304 * 2;
    u16* vt  = (u16*)w; w += (size_t)96 * 64 * 1024 * 2;
    u16* ao  = (u16*)w; w += (size_t)8192 * 768 * 2;

    k_convert<<<dim3(6144), 256, 0, stream>>>(x, xb, 1572864);
    k_transpose_bf<<<dim3(72, 24), dim3(32, 8), 0, stream>>>(W_qkv, wqt, 768, 2304);
    k_transpose_bf<<<dim3(24, 24), dim3(32, 8), 0, stream>>>(W_out, wot, 768, 768);
    k_gemm_bt<2><<<dim3(64, 18), 256, 0, stream>>>(xb, wqt, b_qkv, nullptr, qkv, 8192, 2304, 768);
    k_vt<<<dim3(32, 2, 96), dim3(32, 8), 0, stream>>>(qkv, vt);
    k_attn<<<dim3(768), 256, 0, stream>>>(qkv, vt, ao);
    k_gemm_bt<0><<<dim3(64, 6), 256, 0, stream>>>(ao, wot, b_out, out, nullptr, 8192, 768, 768);
}